// Round 2
// baseline (1097.492 us; speedup 1.0000x reference)
//
#include <hip/hip_runtime.h>
#include <hip/hip_fp8.h>

// Problem constants
#define NB   2048   // batch
#define SEQ  168    // encoder steps
#define NF   7      // features
#define NH   128    // hidden
#define NP   96     // decoder steps
#define EROWS 8     // encoder rows/block -> 256 blocks
#define DROWS 8     // decoder rows/block -> 256 blocks, 1/CU, ONE round
#define NTHR 512
#define KE   160    // enc A/B K: [x 0..6][pad 7][h 8..135][pad 136..159]
#define KD   256    // dec A/B K: [combine 0..127][prev_h 128..255]
#define HXS  168    // h16 row stride for enc MFMA-A tile
#define CTS  264    // cath row stride in h16
#define LS4  30     // s4 groups LDS-resident (s 0..119); tail 12 s4 in registers

typedef _Float16 h16;
typedef _Float16 h16x8 __attribute__((ext_vector_type(8)));
typedef float    f32x2 __attribute__((ext_vector_type(2)));
typedef float    f32x4 __attribute__((ext_vector_type(4)));
typedef unsigned int u32x4 __attribute__((ext_vector_type(4)));

// -------- d_ws layout (bytes). Total 45,613,056. --------
constexpr size_t WENC_OFF   = 0;         // h16[512][160]
constexpr size_t WDEC_OFF   = 163840;    // h16[512][256]
constexpr size_t WEFF_OFF   = 425984;    // h16[168][128]  W_att_h + W_out^T W_att_y
constexpr size_t BEFF_OFF   = 468992;    // f32[168]
constexpr size_t WCOMB_OFF  = 469760;    // f32[128]  W_out^T @ W_fin^T
constexpr size_t BCONST_OFF = 470272;    // f32[1]
constexpr size_t BENC_OFF   = 470528;    // f32[512]
constexpr size_t BDEC_OFF   = 472576;    // f32[512]
constexpr size_t ENC_OFF    = 524288;    // u32[NB][30][128] fp8x4 hist (s4 0..29)   31,457,280 B
constexpr size_t ENC2_OFF   = 31981568;  // u32[NB][3][128][4] hist tail (s4 30..41) 12,582,912 B
constexpr size_t HT_OFF     = 44564480;  // f32[NB*NH] final encoder h (1 MB)

// -------- decoder dynamic-LDS layout (bytes) --------
constexpr int HIST_OFF = 0;        // u32[8][30][128]  122880
constexpr int CATH_OFF = 122880;   // h16[2][8][CTS]     8448 -> 131328
constexpr int ATTW_OFF = 131328;   // f32[8][168]        5376 -> 136704
constexpr int WAT2_OFF = 136704;   // h16[40][128] Weff rows 128..167  10240 -> 146944
constexpr int D0_OFF   = 146944;   // f32[8][168] step-0 y-delta  5376 -> 152320
constexpr int OUTP_OFF = 152320;   // f32[8][8] out partials       256 -> 152576
constexpr int YH_OFF   = 152576;   // f32[56] yh scratch           256 -> 152832
constexpr int DSMEM    = 152832;

__device__ __forceinline__ float sigm(float x) { return 1.f / (1.f + __expf(-x)); }
__device__ __forceinline__ float tanh_(float x) {
  float e = __expf(-2.f * fabsf(x));
  return copysignf((1.f - e) / (1.f + e), x);
}

template <bool HI>
__device__ __forceinline__ unsigned int pack2_fp8(float a, float b, unsigned int old) {
#if __has_builtin(__builtin_amdgcn_cvt_pk_fp8_f32)
  return (unsigned int)__builtin_amdgcn_cvt_pk_fp8_f32(a, b, (int)old, HI);
#else
  __hip_fp8_e4m3 qa(a), qb(b);
  unsigned int pair = (unsigned int)(*(unsigned char*)&qa) |
                      ((unsigned int)(*(unsigned char*)&qb) << 8);
  return HI ? ((old & 0x0000ffffu) | (pair << 16)) : ((old & 0xffff0000u) | pair);
#endif
}
template <bool HI>
__device__ __forceinline__ f32x2 unp2(unsigned int w) {
#if __has_builtin(__builtin_amdgcn_cvt_pk_f32_fp8)
  return __builtin_amdgcn_cvt_pk_f32_fp8(w, HI);
#else
  __hip_fp8_e4m3 a, b;
  constexpr unsigned int sh = HI ? 16 : 0;
  *(unsigned char*)&a = (w >> sh) & 0xff;
  *(unsigned char*)&b = (w >> (sh + 8)) & 0xff;
  f32x2 r; r.x = (float)a; r.y = (float)b; return r;
#endif
}

// -------- setup: cast/pack weights + algebraic folds into ws --------
__global__ void setup_weights(const float* __restrict__ Wih_enc, const float* __restrict__ Whh_enc,
                              const float* __restrict__ Wih_dec, const float* __restrict__ Whh_dec,
                              const float* __restrict__ Watt, const float* __restrict__ batt,
                              const float* __restrict__ Wout, const float* __restrict__ bout,
                              const float* __restrict__ Wfin, const float* __restrict__ bfin,
                              const float* __restrict__ bihe, const float* __restrict__ bhhe,
                              const float* __restrict__ bihd, const float* __restrict__ bhhd,
                              char* __restrict__ ws) {
  int idx = blockIdx.x * blockDim.x + threadIdx.x;
  constexpr int A0 = 81920;            // enc W
  constexpr int A1 = A0 + 131072;      // dec W
  constexpr int A2 = A1 + 21504;       // Weff
  constexpr int A3 = A2 + 168;         // beff
  constexpr int A4 = A3 + 128;         // wcomb
  constexpr int A5 = A4 + 1;           // bconst
  constexpr int A6 = A5 + 512;         // biases
  if (idx < A0) {
    int n = idx / KE, k = idx % KE;
    float v = 0.f;
    if (k < NF) v = Wih_enc[n * NF + k];
    else if (k >= 8 && k < 136) v = Whh_enc[n * NH + (k - 8)];
    ((h16*)(ws + WENC_OFF))[idx] = (h16)v;
  } else if (idx < A1) {
    int i = idx - A0;
    int n = i / KD, k = i % KD;
    float v = (k < NH) ? Wih_dec[n * NH + k] : Whh_dec[n * NH + (k - NH)];
    ((h16*)(ws + WDEC_OFF))[i] = (h16)v;
  } else if (idx < A2) {
    int i = idx - A1;
    int s = i / NH, k = i % NH;
    float v = Watt[s * (NH + NF) + k];
    #pragma unroll
    for (int f = 0; f < NF; ++f)
      v += Watt[s * (NH + NF) + NH + f] * Wout[f * NH + k];
    ((h16*)(ws + WEFF_OFF))[i] = (h16)v;
  } else if (idx < A3) {
    int s = idx - A2;
    float v = batt[s];
    #pragma unroll
    for (int f = 0; f < NF; ++f)
      v += Watt[s * (NH + NF) + NH + f] * bout[f];
    ((float*)(ws + BEFF_OFF))[s] = v;
  } else if (idx < A4) {
    int k = idx - A3;
    float v = 0.f;
    #pragma unroll
    for (int f = 0; f < NF; ++f) v += Wfin[f] * Wout[f * NH + k];
    ((float*)(ws + WCOMB_OFF))[k] = v;
  } else if (idx < A5) {
    float v = bfin[0];
    #pragma unroll
    for (int f = 0; f < NF; ++f) v += bout[f] * Wfin[f];
    ((float*)(ws + BCONST_OFF))[0] = v;
  } else if (idx < A6) {
    int g = idx - A5;
    ((float*)(ws + BENC_OFF))[g] = bihe[g] + bhhe[g];
    ((float*)(ws + BDEC_OFF))[g] = bihd[g] + bhhd[g];
  }
}

// ================= encoder: 8 rows/block, 256 blocks, 1 barrier/step =================
// waves_per_eu(2,2): grid=256 -> 1 block/CU regardless; give allocator 256 VGPRs so
// bfE (80 regs) stays truly register-resident across all 168 steps (no remat/spill).
__global__ __attribute__((amdgpu_flat_work_group_size(NTHR, NTHR), amdgpu_waves_per_eu(2, 2)))
void enc_kernel(const float* __restrict__ xb, const h16* __restrict__ w16enc,
                const float* __restrict__ bencp, unsigned int* __restrict__ encw,
                unsigned int* __restrict__ encw2, float* __restrict__ hT) {
  __shared__ alignas(16) h16 sh_hx[2][16][HXS];

  const int t  = threadIdx.x;
  const int r0 = blockIdx.x * EROWS;

  for (int i = t; i < 2 * 16 * HXS; i += NTHR) ((h16*)sh_hx)[i] = (h16)0.f;
  __syncthreads();
  if (t < EROWS * NF) {
    int r = t / NF, f = t - (t / NF) * NF;
    sh_hx[0][r][f] = (h16)xb[((size_t)(r0 + r) * SEQ + 0) * NF + f];
  }

  const int w  = t >> 6;
  const int l  = t & 63;
  const int lq = l >> 4;
  const int ln = l & 15;
  const int hcol = w * 16 + ln;
  const int mrow = lq * 4;
  const bool act = (lq < 2);

  const int j  = t & 3;
  const int rf = t >> 2;
  const int xr = rf / NF;
  const int xf = rf - xr * NF;

  h16x8 bfE[4][5];
  float bE[4];
  #pragma unroll
  for (int g = 0; g < 4; ++g) {
    int n = g * 128 + hcol;
    bE[g] = bencp[n];
    #pragma unroll
    for (int kt = 0; kt < 5; ++kt)
      bfE[g][kt] = *(const h16x8*)(w16enc + n * KE + kt * 32 + lq * 8);
  }

  float creg[4] = {0.f, 0.f, 0.f, 0.f};
  float hlast[4] = {0.f, 0.f, 0.f, 0.f};
  float hprev[4] = {0.f, 0.f, 0.f, 0.f};
  unsigned int hpack[4] = {0u, 0u, 0u, 0u};
  float xstash = 0.f;

  __syncthreads();

  for (int s = 0; s < SEQ; ++s) {
    const int cur = s & 1;
    if ((s & 3) == 0 && t < EROWS * NF * 4) {
      int sx = s + 1 + j;
      xstash = (sx < SEQ) ? xb[((size_t)(r0 + xr) * SEQ + sx) * NF + xf] : 0.f;
    }

    h16x8 af[5];
    #pragma unroll
    for (int kt = 0; kt < 5; ++kt)
      af[kt] = *(const h16x8*)(&sh_hx[cur][ln][kt * 32 + lq * 8]);
    f32x4 ac[4];
    #pragma unroll
    for (int g = 0; g < 4; ++g) {
      f32x4 a = {0.f, 0.f, 0.f, 0.f};
      #pragma unroll
      for (int kt = 0; kt < 5; ++kt)
        a = __builtin_amdgcn_mfma_f32_16x16x32_f16(af[kt], bfE[g][kt], a, 0, 0, 0);
      ac[g] = a;
    }

    if (act) {
      #pragma unroll
      for (int reg = 0; reg < 4; ++reg) {
        float gi = sigm(ac[0][reg] + bE[0]);
        float gf = sigm(ac[1][reg] + bE[1]);
        float gg = tanh_(ac[2][reg] + bE[2]);
        float go = sigm(ac[3][reg] + bE[3]);
        float c = gf * creg[reg] + gi * gg;
        creg[reg] = c;
        float h = go * tanh_(c);
        hlast[reg] = h;
        sh_hx[cur ^ 1][mrow + reg][8 + hcol] = (h16)h;
        float hs = h * 16.f;
        if ((s & 1) == 0) hprev[reg] = hs;
        else if ((s & 3) == 1) hpack[reg] = pack2_fp8<false>(hprev[reg], hs, hpack[reg]);
        else                   hpack[reg] = pack2_fp8<true>(hprev[reg], hs, hpack[reg]);
      }
      if ((s & 3) == 3) {
        int s4 = s >> 2;
        if (s4 < LS4) {
          #pragma unroll
          for (int reg = 0; reg < 4; ++reg)
            encw[((size_t)(r0 + mrow + reg) * LS4 + s4) * NH + hcol] = hpack[reg];
        } else {
          int q = s4 - LS4;          // 0..11 -> blk = q>>2, lane jj = q&3
          #pragma unroll
          for (int reg = 0; reg < 4; ++reg)
            encw2[(((size_t)(r0 + mrow + reg) * 3 + (q >> 2)) * NH + hcol) * 4 + (q & 3)] = hpack[reg];
        }
      }
    }
    if (t < EROWS * NF * 4 && (s & 3) == j && s + 1 < SEQ)
      sh_hx[cur ^ 1][xr][xf] = (h16)xstash;
    __syncthreads();
  }

  if (act) {
    #pragma unroll
    for (int reg = 0; reg < 4; ++reg)
      hT[(size_t)(r0 + mrow + reg) * NH + hcol] = hlast[reg];
  }
}

// ================= decoder: 8 rows/block, 256 blocks (ONE round), hist LDS+regs ======
// waves_per_eu(2,2): LDS (153 KB) already caps at 1 block/CU = 2 waves/EU, so allow the
// full 256 VGPRs/wave that occupancy level permits. Need ~210 (bfD 96 + bfA 16 + tails
// 24 + temps). Round-1 cap of 128 caused ~33 MB/dispatch scratch spill traffic.
__global__ __attribute__((amdgpu_flat_work_group_size(NTHR, NTHR), amdgpu_waves_per_eu(2, 2)))
void dec_kernel(const float* __restrict__ xb, const float* __restrict__ Watt,
                const float* __restrict__ Wout, const float* __restrict__ bout,
                const h16* __restrict__ w16dec, const h16* __restrict__ weff,
                const float* __restrict__ beffp, const float* __restrict__ wcombp,
                const float* __restrict__ bconstp, const float* __restrict__ bdecp,
                const unsigned int* __restrict__ encw, const unsigned int* __restrict__ encw2,
                const float* __restrict__ hT, float* __restrict__ out) {
  extern __shared__ char smem[];
  unsigned int* hist = (unsigned int*)(smem + HIST_OFF);   // [8][30][128] u32
  h16*   sh_cath  = (h16*)(smem + CATH_OFF);               // [2][8][CTS]
  float* sh_attw  = (float*)(smem + ATTW_OFF);             // [8][168] e-values
  h16*   sh_watt2 = (h16*)(smem + WAT2_OFF);               // [40][128] Weff tail
  float* sh_d0    = (float*)(smem + D0_OFF);               // [8][168] step-0 delta
  float* sh_outp  = (float*)(smem + OUTP_OFF);             // [8][8] out partials
  float* sh_yh    = (float*)(smem + YH_OFF);               // [56]

  const int t  = threadIdx.x;
  const int r0 = blockIdx.x * DROWS;

  // ---- init LDS ----
  for (int i = t; i < 2 * 8 * CTS; i += NTHR)   sh_cath[i] = (h16)0.f;
  for (int i = t; i < 40 * NH; i += NTHR)       sh_watt2[i] = weff[128 * NH + i];
  {
    const u32x4* src = (const u32x4*)(encw + (size_t)r0 * LS4 * NH);
    for (int i = t; i < (DROWS * LS4 * NH) / 4; i += NTHR)
      ((u32x4*)hist)[i] = src[i];
  }

  const int w  = t >> 6;
  const int l  = t & 63;
  const int lq = l >> 4;
  const int ln = l & 15;
  const int hcol = w * 16 + ln;
  const bool act = (lq < 2);   // C rows lq*4+reg = 0..7 real

  // B fragments: dec gates (i,f,g) K=256; Weff tile K=128
  h16x8 bfD[3][8];
  float bD[3];
  #pragma unroll
  for (int g = 0; g < 3; ++g) {
    int n = g * 128 + hcol;
    bD[g] = bdecp[n];
    #pragma unroll
    for (int kt = 0; kt < 8; ++kt)
      bfD[g][kt] = *(const h16x8*)(w16dec + n * KD + kt * 32 + lq * 8);
  }
  h16x8 bfA[4];
  #pragma unroll
  for (int kt = 0; kt < 4; ++kt)
    bfA[kt] = *(const h16x8*)(weff + hcol * NH + kt * 32 + lq * 8);
  const float beffR = beffp[hcol];
  const int s2v = 128 + hcol;
  const float beff2 = (w < 3 && s2v < SEQ) ? beffp[s2v] : 0.f;
  const float wcombR = wcombp[hcol];
  const float bconstv = bconstp[0];

  // cell init from h_T; prev_h into cath[0]
  float creg[4] = {0.f, 0.f, 0.f, 0.f};
  if (act) {
    #pragma unroll
    for (int reg = 0; reg < 4; ++reg) {
      int row = lq * 4 + reg;
      float hv = hT[(size_t)(r0 + row) * NH + hcol];
      creg[reg] = hv;
      sh_cath[0 * 8 * CTS + row * CTS + 128 + hcol] = (h16)hv;
    }
  }
  // yh[r][f] = h_T . W_out[f] + bout[f]  (one-time)
  if (t < DROWS * NF) {
    int r = t / NF, f = t - (t / NF) * NF;
    float a = bout[f];
    const float* wr = Wout + f * NH;
    const float* hp = hT + (size_t)(r0 + r) * NH;
    #pragma unroll 8
    for (int k = 0; k < NH; k += 4) {
      float4 pv = *(const float4*)(hp + k);
      float4 wv = *(const float4*)(wr + k);
      a += pv.x * wv.x + pv.y * wv.y + pv.z * wv.z + pv.w * wv.w;
    }
    sh_yh[t] = a;
  }
  __syncthreads();
  // d0[r][s] = (y0[r] - yh[r]) . W_att_y[s]  (step-0 correction)
  for (int i = t; i < DROWS * SEQ; i += NTHR) {
    int r = i / SEQ, s = i - (i / SEQ) * SEQ;
    float a = 0.f;
    #pragma unroll
    for (int f = 0; f < NF; ++f) {
      float y0f = xb[((size_t)(r0 + r) * SEQ + (SEQ - 1)) * NF + f];
      a += (y0f - sh_yh[r * NF + f]) * Watt[s * (NH + NF) + NH + f];
    }
    sh_d0[i] = a;
  }

  // D3 per-thread constants: each thread owns (dh) for rows dr and dr+4
  const int dr = t >> 7;          // 0..3 (wave-uniform)
  const int dh = t & 127;
  const unsigned int* hrowA = hist + (size_t)dr * (LS4 * NH) + dh;
  const unsigned int* hrowB = hist + (size_t)(dr + 4) * (LS4 * NH) + dh;
  const float* erowA = sh_attw + dr * SEQ;
  const float* erowB = sh_attw + (dr + 4) * SEQ;

  // step-invariant hist tail (s4 30..41) held in registers: 3x u32x4 per row
  u32x4 tA[3], tB[3];
  {
    const u32x4* e2 = (const u32x4*)encw2;
    #pragma unroll
    for (int b = 0; b < 3; ++b) {
      tA[b] = e2[((size_t)(r0 + dr)     * 3 + b) * NH + dh];
      tB[b] = e2[((size_t)(r0 + dr + 4) * 3 + b) * NH + dh];
    }
  }
  __syncthreads();

  for (int p = 0; p < NP; ++p) {
    const int CA = p & 1;

    // finalize previous step's output (partials written in prev D4)
    if (p > 0 && t < DROWS) {
      float a = bconstv;
      #pragma unroll
      for (int w2 = 0; w2 < 8; ++w2) a += sh_outp[w2 * 8 + t];
      out[(size_t)(r0 + t) * NP + (p - 1)] = a;
    }

    // D1: logits = prev_h @ Weff^T + beff (+d0 at p=0); e = exp(clamped)
    {
      h16x8 afA[4];
      #pragma unroll
      for (int kt = 0; kt < 4; ++kt)
        afA[kt] = *(const h16x8*)(sh_cath + CA * 8 * CTS + (ln & 7) * CTS + 128 + kt * 32 + lq * 8);
      f32x4 acc = {0.f, 0.f, 0.f, 0.f};
      #pragma unroll
      for (int kt = 0; kt < 4; ++kt)
        acc = __builtin_amdgcn_mfma_f32_16x16x32_f16(afA[kt], bfA[kt], acc, 0, 0, 0);
      if (act) {
        #pragma unroll
        for (int reg = 0; reg < 4; ++reg) {
          int row = lq * 4 + reg;
          float lg = acc[reg] + beffR;
          if (p == 0) lg += sh_d0[row * SEQ + hcol];
          lg = fminf(fmaxf(lg, -30.f), 30.f);
          sh_attw[row * SEQ + hcol] = __expf(lg);
        }
      }
      if (w < 3) {
        int srow = (s2v < SEQ ? s2v : SEQ - 1) - 128;
        f32x4 acc2 = {0.f, 0.f, 0.f, 0.f};
        #pragma unroll
        for (int kt = 0; kt < 4; ++kt) {
          h16x8 bf2 = *(const h16x8*)(sh_watt2 + srow * NH + kt * 32 + lq * 8);
          acc2 = __builtin_amdgcn_mfma_f32_16x16x32_f16(afA[kt], bf2, acc2, 0, 0, 0);
        }
        if (s2v < SEQ && act) {
          #pragma unroll
          for (int reg = 0; reg < 4; ++reg) {
            int row = lq * 4 + reg;
            float lg = acc2[reg] + beff2;
            if (p == 0) lg += sh_d0[row * SEQ + s2v];
            lg = fminf(fmaxf(lg, -30.f), 30.f);
            sh_attw[row * SEQ + s2v] = __expf(lg);
          }
        }
      }
    }
    __syncthreads();

    // D3: combine[r][h] = (Σ_s e_s v_s)/(Σ_s e_s); thread owns (dh) x rows {dr, dr+4}
    {
      // denominators via wave-wide shuffle reduce over sh_attw (rows are wave-uniform)
      float dA = erowA[l] + erowA[64 + l];
      float dB = erowB[l] + erowB[64 + l];
      if (l < SEQ - 128) { dA += erowA[128 + l]; dB += erowB[128 + l]; }
      #pragma unroll
      for (int k = 1; k < 64; k <<= 1) {
        dA += __shfl_xor(dA, k);
        dB += __shfl_xor(dB, k);
      }
      const float invA = 0.0625f / dA;
      const float invB = 0.0625f / dB;

      f32x2 avA = {0.f, 0.f};
      f32x2 avB = {0.f, 0.f};
      #pragma unroll 6
      for (int s4 = 0; s4 < LS4; ++s4) {
        unsigned int evA = hrowA[s4 * NH];
        unsigned int evB = hrowB[s4 * NH];
        float4 eA = *(const float4*)(erowA + s4 * 4);
        float4 eB = *(const float4*)(erowB + s4 * 4);
        f32x2 wA01 = {eA.x, eA.y}, wA23 = {eA.z, eA.w};
        f32x2 wB01 = {eB.x, eB.y}, wB23 = {eB.z, eB.w};
        avA = wA01 * unp2<false>(evA) + avA;
        avA = wA23 * unp2<true>(evA) + avA;
        avB = wB01 * unp2<false>(evB) + avB;
        avB = wB23 * unp2<true>(evB) + avB;
      }
      #pragma unroll
      for (int b = 0; b < 3; ++b) {
        #pragma unroll
        for (int jj = 0; jj < 4; ++jj) {
          int s4 = LS4 + b * 4 + jj;
          unsigned int evA = tA[b][jj];
          unsigned int evB = tB[b][jj];
          float4 eA = *(const float4*)(erowA + s4 * 4);
          float4 eB = *(const float4*)(erowB + s4 * 4);
          f32x2 wA01 = {eA.x, eA.y}, wA23 = {eA.z, eA.w};
          f32x2 wB01 = {eB.x, eB.y}, wB23 = {eB.z, eB.w};
          avA = wA01 * unp2<false>(evA) + avA;
          avA = wA23 * unp2<true>(evA) + avA;
          avB = wB01 * unp2<false>(evB) + avB;
          avB = wB23 * unp2<true>(evB) + avB;
        }
      }
      sh_cath[CA * 8 * CTS + dr * CTS + dh]       = (h16)((avA.x + avA.y) * invA);
      sh_cath[CA * 8 * CTS + (dr + 4) * CTS + dh] = (h16)((avB.x + avB.y) * invB);
    }
    __syncthreads();

    // D4+D5: gates via MFMA (i,f,g); cell in-register; out-partials via wcomb
    {
      h16x8 af[8];
      #pragma unroll
      for (int kt = 0; kt < 8; ++kt)
        af[kt] = *(const h16x8*)(sh_cath + CA * 8 * CTS + (ln & 7) * CTS + kt * 32 + lq * 8);
      f32x4 ag[3];
      #pragma unroll
      for (int g = 0; g < 3; ++g) {
        f32x4 a = {0.f, 0.f, 0.f, 0.f};
        #pragma unroll
        for (int kt = 0; kt < 8; ++kt)
          a = __builtin_amdgcn_mfma_f32_16x16x32_f16(af[kt], bfD[g][kt], a, 0, 0, 0);
        ag[g] = a;
      }
      if (act) {
        float contrib[4];
        #pragma unroll
        for (int reg = 0; reg < 4; ++reg) {
          int row = lq * 4 + reg;
          float gi = sigm(ag[0][reg] + bD[0]);
          float gf = sigm(ag[1][reg] + bD[1]);
          float gg = tanh_(ag[2][reg] + bD[2]);
          float cn = gf * creg[reg] + gi * gg;
          creg[reg] = cn;
          sh_cath[(CA ^ 1) * 8 * CTS + row * CTS + 128 + hcol] = (h16)cn;
          contrib[reg] = cn * wcombR;
        }
        #pragma unroll
        for (int reg = 0; reg < 4; ++reg) {
          float rsum = contrib[reg];
          rsum += __shfl_xor(rsum, 1);
          rsum += __shfl_xor(rsum, 2);
          rsum += __shfl_xor(rsum, 4);
          rsum += __shfl_xor(rsum, 8);
          if (ln == 0) sh_outp[w * 8 + lq * 4 + reg] = rsum;
        }
      }
    }
    __syncthreads();
  }

  // finalize last output
  if (t < DROWS) {
    float a = bconstv;
    #pragma unroll
    for (int w2 = 0; w2 < 8; ++w2) a += sh_outp[w2 * 8 + t];
    out[(size_t)(r0 + t) * NP + (NP - 1)] = a;
  }
}

extern "C" void kernel_launch(void* const* d_in, const int* in_sizes, int n_in,
                              void* d_out, int out_size, void* d_ws, size_t ws_size,
                              hipStream_t stream) {
  const float* xb      = (const float*)d_in[0];
  const float* Wih_enc = (const float*)d_in[1];
  const float* Whh_enc = (const float*)d_in[2];
  const float* bih_enc = (const float*)d_in[3];
  const float* bhh_enc = (const float*)d_in[4];
  const float* Watt    = (const float*)d_in[5];
  const float* batt    = (const float*)d_in[6];
  const float* Wih_dec = (const float*)d_in[7];
  const float* Whh_dec = (const float*)d_in[8];
  const float* bih_dec = (const float*)d_in[9];
  const float* bhh_dec = (const float*)d_in[10];
  const float* Wout    = (const float*)d_in[11];
  const float* bout    = (const float*)d_in[12];
  const float* Wfin    = (const float*)d_in[13];
  const float* bfin    = (const float*)d_in[14];
  char* ws = (char*)d_ws;  // needs ~45.6 MB

  hipFuncSetAttribute(reinterpret_cast<const void*>(dec_kernel),
                      hipFuncAttributeMaxDynamicSharedMemorySize, DSMEM);

  // 81920+131072+21504+168+128+1+512 = 235305 -> 920 blocks
  setup_weights<<<920, 256, 0, stream>>>(Wih_enc, Whh_enc, Wih_dec, Whh_dec,
                                         Watt, batt, Wout, bout, Wfin, bfin,
                                         bih_enc, bhh_enc, bih_dec, bhh_dec, ws);
  enc_kernel<<<NB / EROWS, NTHR, 0, stream>>>(
      xb, (const h16*)(ws + WENC_OFF), (const float*)(ws + BENC_OFF),
      (unsigned int*)(ws + ENC_OFF), (unsigned int*)(ws + ENC2_OFF),
      (float*)(ws + HT_OFF));
  dec_kernel<<<NB / DROWS, NTHR, DSMEM, stream>>>(
      xb, Watt, Wout, bout,
      (const h16*)(ws + WDEC_OFF), (const h16*)(ws + WEFF_OFF),
      (const float*)(ws + BEFF_OFF), (const float*)(ws + WCOMB_OFF),
      (const float*)(ws + BCONST_OFF), (const float*)(ws + BDEC_OFF),
      (const unsigned int*)(ws + ENC_OFF), (const unsigned int*)(ws + ENC2_OFF),
      (const float*)(ws + HT_OFF), (float*)d_out);
}

// Round 3
// 929.082 us; speedup vs baseline: 1.1813x; 1.1813x over previous
//
#include <hip/hip_runtime.h>
#include <hip/hip_fp8.h>

// Problem constants
#define NB   2048   // batch
#define SEQ  168    // encoder steps
#define NF   7      // features
#define NH   128    // hidden
#define NP   96     // decoder steps
#define EROWS 8     // encoder rows/block -> 256 blocks
#define DROWS 8     // decoder rows/block -> 256 blocks, 1/CU, ONE round
#define NTHR 512
#define KE   160    // enc A/B K: [x 0..6][pad 7][h 8..135][pad 136..159]
#define KD   256    // dec A/B K: [combine 0..127][prev_h 128..255]
#define HXS  168    // h16 row stride for enc MFMA-A tile
#define CTS  264    // cath row stride in h16
#define LS4  30     // s4 groups LDS-resident (s 0..119); tail 12 s4 in registers

typedef _Float16 h16;
typedef _Float16 h16x8 __attribute__((ext_vector_type(8)));
typedef float    f32x2 __attribute__((ext_vector_type(2)));
typedef float    f32x4 __attribute__((ext_vector_type(4)));
typedef unsigned int u32x4 __attribute__((ext_vector_type(4)));

// MFMA with B operand sourced DIRECTLY from AGPRs (gfx950 allows AGPR A/B).
// This gives the step-invariant weight fragments dedicated storage in the
// accumulator half of the unified RF, escaping the 128-arch-VGPR allocator cap
// that caused 33 MB/dispatch scratch spill traffic in rounds 1-2.
__device__ __forceinline__ void mfma_av(f32x4& acc, h16x8 a, const h16x8& b_agpr) {
  asm("v_mfma_f32_16x16x32_f16 %0, %1, %2, %0"
      : "+v"(acc) : "v"(a), "a"(b_agpr));
}
// Pin a loaded fragment into AGPR class at init (one-time v_accvgpr_write x4).
#define PIN_A(x) asm volatile("" : "+a"(x))

__device__ __forceinline__ float sigm(float x) { return 1.f / (1.f + __expf(-x)); }
__device__ __forceinline__ float tanh_(float x) {
  float e = __expf(-2.f * fabsf(x));
  return copysignf((1.f - e) / (1.f + e), x);
}

template <bool HI>
__device__ __forceinline__ unsigned int pack2_fp8(float a, float b, unsigned int old) {
#if __has_builtin(__builtin_amdgcn_cvt_pk_fp8_f32)
  return (unsigned int)__builtin_amdgcn_cvt_pk_fp8_f32(a, b, (int)old, HI);
#else
  __hip_fp8_e4m3 qa(a), qb(b);
  unsigned int pair = (unsigned int)(*(unsigned char*)&qa) |
                      ((unsigned int)(*(unsigned char*)&qb) << 8);
  return HI ? ((old & 0x0000ffffu) | (pair << 16)) : ((old & 0xffff0000u) | pair);
#endif
}
template <bool HI>
__device__ __forceinline__ f32x2 unp2(unsigned int w) {
#if __has_builtin(__builtin_amdgcn_cvt_pk_f32_fp8)
  return __builtin_amdgcn_cvt_pk_f32_fp8(w, HI);
#else
  __hip_fp8_e4m3 a, b;
  constexpr unsigned int sh = HI ? 16 : 0;
  *(unsigned char*)&a = (w >> sh) & 0xff;
  *(unsigned char*)&b = (w >> (sh + 8)) & 0xff;
  f32x2 r; r.x = (float)a; r.y = (float)b; return r;
#endif
}

// -------- d_ws layout (bytes). Total 45,613,056. --------
constexpr size_t WENC_OFF   = 0;         // h16[512][160]
constexpr size_t WDEC_OFF   = 163840;    // h16[512][256]
constexpr size_t WEFF_OFF   = 425984;    // h16[168][128]  W_att_h + W_out^T W_att_y
constexpr size_t BEFF_OFF   = 468992;    // f32[168]
constexpr size_t WCOMB_OFF  = 469760;    // f32[128]  W_out^T @ W_fin^T
constexpr size_t BCONST_OFF = 470272;    // f32[1]
constexpr size_t BENC_OFF   = 470528;    // f32[512]
constexpr size_t BDEC_OFF   = 472576;    // f32[512]
constexpr size_t ENC_OFF    = 524288;    // u32[NB][30][128] fp8x4 hist (s4 0..29)   31,457,280 B
constexpr size_t ENC2_OFF   = 31981568;  // u32[NB][3][128][4] hist tail (s4 30..41) 12,582,912 B
constexpr size_t HT_OFF     = 44564480;  // f32[NB*NH] final encoder h (1 MB)

// -------- decoder dynamic-LDS layout (bytes) --------
constexpr int HIST_OFF = 0;        // u32[8][30][128]  122880
constexpr int CATH_OFF = 122880;   // h16[2][8][CTS]     8448 -> 131328
constexpr int ATTW_OFF = 131328;   // f32[8][168]        5376 -> 136704
constexpr int WAT2_OFF = 136704;   // h16[40][128] Weff rows 128..167  10240 -> 146944
constexpr int D0_OFF   = 146944;   // f32[8][168] step-0 y-delta  5376 -> 152320
constexpr int OUTP_OFF = 152320;   // f32[8][8] out partials       256 -> 152576
constexpr int YH_OFF   = 152576;   // f32[56] yh scratch           256 -> 152832
constexpr int DSMEM    = 152832;

// -------- setup: cast/pack weights + algebraic folds into ws --------
__global__ void setup_weights(const float* __restrict__ Wih_enc, const float* __restrict__ Whh_enc,
                              const float* __restrict__ Wih_dec, const float* __restrict__ Whh_dec,
                              const float* __restrict__ Watt, const float* __restrict__ batt,
                              const float* __restrict__ Wout, const float* __restrict__ bout,
                              const float* __restrict__ Wfin, const float* __restrict__ bfin,
                              const float* __restrict__ bihe, const float* __restrict__ bhhe,
                              const float* __restrict__ bihd, const float* __restrict__ bhhd,
                              char* __restrict__ ws) {
  int idx = blockIdx.x * blockDim.x + threadIdx.x;
  constexpr int A0 = 81920;            // enc W
  constexpr int A1 = A0 + 131072;      // dec W
  constexpr int A2 = A1 + 21504;       // Weff
  constexpr int A3 = A2 + 168;         // beff
  constexpr int A4 = A3 + 128;         // wcomb
  constexpr int A5 = A4 + 1;           // bconst
  constexpr int A6 = A5 + 512;         // biases
  if (idx < A0) {
    int n = idx / KE, k = idx % KE;
    float v = 0.f;
    if (k < NF) v = Wih_enc[n * NF + k];
    else if (k >= 8 && k < 136) v = Whh_enc[n * NH + (k - 8)];
    ((h16*)(ws + WENC_OFF))[idx] = (h16)v;
  } else if (idx < A1) {
    int i = idx - A0;
    int n = i / KD, k = i % KD;
    float v = (k < NH) ? Wih_dec[n * NH + k] : Whh_dec[n * NH + (k - NH)];
    ((h16*)(ws + WDEC_OFF))[i] = (h16)v;
  } else if (idx < A2) {
    int i = idx - A1;
    int s = i / NH, k = i % NH;
    float v = Watt[s * (NH + NF) + k];
    #pragma unroll
    for (int f = 0; f < NF; ++f)
      v += Watt[s * (NH + NF) + NH + f] * Wout[f * NH + k];
    ((h16*)(ws + WEFF_OFF))[i] = (h16)v;
  } else if (idx < A3) {
    int s = idx - A2;
    float v = batt[s];
    #pragma unroll
    for (int f = 0; f < NF; ++f)
      v += Watt[s * (NH + NF) + NH + f] * bout[f];
    ((float*)(ws + BEFF_OFF))[s] = v;
  } else if (idx < A4) {
    int k = idx - A3;
    float v = 0.f;
    #pragma unroll
    for (int f = 0; f < NF; ++f) v += Wfin[f] * Wout[f * NH + k];
    ((float*)(ws + WCOMB_OFF))[k] = v;
  } else if (idx < A5) {
    float v = bfin[0];
    #pragma unroll
    for (int f = 0; f < NF; ++f) v += bout[f] * Wfin[f];
    ((float*)(ws + BCONST_OFF))[0] = v;
  } else if (idx < A6) {
    int g = idx - A5;
    ((float*)(ws + BENC_OFF))[g] = bihe[g] + bhhe[g];
    ((float*)(ws + BDEC_OFF))[g] = bihd[g] + bhhd[g];
  }
}

// ================= encoder: 8 rows/block, 256 blocks, 1 barrier/step =================
// bfE (80 regs of weights) pinned in AGPRs; MFMA reads B from AGPR directly.
__global__ __attribute__((amdgpu_flat_work_group_size(NTHR, NTHR), amdgpu_waves_per_eu(2, 2)))
void enc_kernel(const float* __restrict__ xb, const h16* __restrict__ w16enc,
                const float* __restrict__ bencp, unsigned int* __restrict__ encw,
                unsigned int* __restrict__ encw2, float* __restrict__ hT) {
  __shared__ alignas(16) h16 sh_hx[2][16][HXS];

  const int t  = threadIdx.x;
  const int r0 = blockIdx.x * EROWS;

  for (int i = t; i < 2 * 16 * HXS; i += NTHR) ((h16*)sh_hx)[i] = (h16)0.f;
  __syncthreads();
  if (t < EROWS * NF) {
    int r = t / NF, f = t - (t / NF) * NF;
    sh_hx[0][r][f] = (h16)xb[((size_t)(r0 + r) * SEQ + 0) * NF + f];
  }

  const int w  = t >> 6;
  const int l  = t & 63;
  const int lq = l >> 4;
  const int ln = l & 15;
  const int hcol = w * 16 + ln;
  const int mrow = lq * 4;
  const bool act = (lq < 2);

  const int j  = t & 3;
  const int rf = t >> 2;
  const int xr = rf / NF;
  const int xf = rf - xr * NF;

  h16x8 bfE[4][5];
  float bE[4];
  #pragma unroll
  for (int g = 0; g < 4; ++g) {
    int n = g * 128 + hcol;
    bE[g] = bencp[n];
    #pragma unroll
    for (int kt = 0; kt < 5; ++kt) {
      bfE[g][kt] = *(const h16x8*)(w16enc + n * KE + kt * 32 + lq * 8);
      PIN_A(bfE[g][kt]);
    }
  }

  float creg[4] = {0.f, 0.f, 0.f, 0.f};
  float hlast[4] = {0.f, 0.f, 0.f, 0.f};
  float hprev[4] = {0.f, 0.f, 0.f, 0.f};
  unsigned int hpack[4] = {0u, 0u, 0u, 0u};
  float xstash = 0.f;

  __syncthreads();

  for (int s = 0; s < SEQ; ++s) {
    const int cur = s & 1;
    if ((s & 3) == 0 && t < EROWS * NF * 4) {
      int sx = s + 1 + j;
      xstash = (sx < SEQ) ? xb[((size_t)(r0 + xr) * SEQ + sx) * NF + xf] : 0.f;
    }

    f32x4 ac[4] = {{0.f,0.f,0.f,0.f},{0.f,0.f,0.f,0.f},{0.f,0.f,0.f,0.f},{0.f,0.f,0.f,0.f}};
    #pragma unroll
    for (int kt = 0; kt < 5; ++kt) {
      h16x8 af = *(const h16x8*)(&sh_hx[cur][ln][kt * 32 + lq * 8]);
      #pragma unroll
      for (int g = 0; g < 4; ++g)
        mfma_av(ac[g], af, bfE[g][kt]);
    }

    if (act) {
      #pragma unroll
      for (int reg = 0; reg < 4; ++reg) {
        float gi = sigm(ac[0][reg] + bE[0]);
        float gf = sigm(ac[1][reg] + bE[1]);
        float gg = tanh_(ac[2][reg] + bE[2]);
        float go = sigm(ac[3][reg] + bE[3]);
        float c = gf * creg[reg] + gi * gg;
        creg[reg] = c;
        float h = go * tanh_(c);
        hlast[reg] = h;
        sh_hx[cur ^ 1][mrow + reg][8 + hcol] = (h16)h;
        float hs = h * 16.f;
        if ((s & 1) == 0) hprev[reg] = hs;
        else if ((s & 3) == 1) hpack[reg] = pack2_fp8<false>(hprev[reg], hs, hpack[reg]);
        else                   hpack[reg] = pack2_fp8<true>(hprev[reg], hs, hpack[reg]);
      }
      if ((s & 3) == 3) {
        int s4 = s >> 2;
        if (s4 < LS4) {
          #pragma unroll
          for (int reg = 0; reg < 4; ++reg)
            encw[((size_t)(r0 + mrow + reg) * LS4 + s4) * NH + hcol] = hpack[reg];
        } else {
          int q = s4 - LS4;          // 0..11 -> blk = q>>2, lane jj = q&3
          #pragma unroll
          for (int reg = 0; reg < 4; ++reg)
            encw2[(((size_t)(r0 + mrow + reg) * 3 + (q >> 2)) * NH + hcol) * 4 + (q & 3)] = hpack[reg];
        }
      }
    }
    if (t < EROWS * NF * 4 && (s & 3) == j && s + 1 < SEQ)
      sh_hx[cur ^ 1][xr][xf] = (h16)xstash;
    __syncthreads();
  }

  if (act) {
    #pragma unroll
    for (int reg = 0; reg < 4; ++reg)
      hT[(size_t)(r0 + mrow + reg) * NH + hcol] = hlast[reg];
  }
}

// ================= decoder: 8 rows/block, 256 blocks (ONE round), hist LDS+regs ======
// bfD (96 regs) + bfA (16 regs) pinned in AGPRs -> arch VGPR pressure ~110, no spill.
__global__ __attribute__((amdgpu_flat_work_group_size(NTHR, NTHR), amdgpu_waves_per_eu(2, 2)))
void dec_kernel(const float* __restrict__ xb, const float* __restrict__ Watt,
                const float* __restrict__ Wout, const float* __restrict__ bout,
                const h16* __restrict__ w16dec, const h16* __restrict__ weff,
                const float* __restrict__ beffp, const float* __restrict__ wcombp,
                const float* __restrict__ bconstp, const float* __restrict__ bdecp,
                const unsigned int* __restrict__ encw, const unsigned int* __restrict__ encw2,
                const float* __restrict__ hT, float* __restrict__ out) {
  extern __shared__ char smem[];
  unsigned int* hist = (unsigned int*)(smem + HIST_OFF);   // [8][30][128] u32
  h16*   sh_cath  = (h16*)(smem + CATH_OFF);               // [2][8][CTS]
  float* sh_attw  = (float*)(smem + ATTW_OFF);             // [8][168] e-values
  h16*   sh_watt2 = (h16*)(smem + WAT2_OFF);               // [40][128] Weff tail
  float* sh_d0    = (float*)(smem + D0_OFF);               // [8][168] step-0 delta
  float* sh_outp  = (float*)(smem + OUTP_OFF);             // [8][8] out partials
  float* sh_yh    = (float*)(smem + YH_OFF);               // [56]

  const int t  = threadIdx.x;
  const int r0 = blockIdx.x * DROWS;

  // ---- init LDS ----
  for (int i = t; i < 2 * 8 * CTS; i += NTHR)   sh_cath[i] = (h16)0.f;
  for (int i = t; i < 40 * NH; i += NTHR)       sh_watt2[i] = weff[128 * NH + i];
  {
    const u32x4* src = (const u32x4*)(encw + (size_t)r0 * LS4 * NH);
    for (int i = t; i < (DROWS * LS4 * NH) / 4; i += NTHR)
      ((u32x4*)hist)[i] = src[i];
  }

  const int w  = t >> 6;
  const int l  = t & 63;
  const int lq = l >> 4;
  const int ln = l & 15;
  const int hcol = w * 16 + ln;
  const bool act = (lq < 2);   // C rows lq*4+reg = 0..7 real

  // B fragments: dec gates (i,f,g) K=256; Weff tile K=128 — pinned to AGPRs
  h16x8 bfD[3][8];
  float bD[3];
  #pragma unroll
  for (int g = 0; g < 3; ++g) {
    int n = g * 128 + hcol;
    bD[g] = bdecp[n];
    #pragma unroll
    for (int kt = 0; kt < 8; ++kt) {
      bfD[g][kt] = *(const h16x8*)(w16dec + n * KD + kt * 32 + lq * 8);
      PIN_A(bfD[g][kt]);
    }
  }
  h16x8 bfA[4];
  #pragma unroll
  for (int kt = 0; kt < 4; ++kt) {
    bfA[kt] = *(const h16x8*)(weff + hcol * NH + kt * 32 + lq * 8);
    PIN_A(bfA[kt]);
  }
  const float beffR = beffp[hcol];
  const int s2v = 128 + hcol;
  const float beff2 = (w < 3 && s2v < SEQ) ? beffp[s2v] : 0.f;
  const float wcombR = wcombp[hcol];
  const float bconstv = bconstp[0];

  // cell init from h_T; prev_h into cath[0]
  float creg[4] = {0.f, 0.f, 0.f, 0.f};
  if (act) {
    #pragma unroll
    for (int reg = 0; reg < 4; ++reg) {
      int row = lq * 4 + reg;
      float hv = hT[(size_t)(r0 + row) * NH + hcol];
      creg[reg] = hv;
      sh_cath[0 * 8 * CTS + row * CTS + 128 + hcol] = (h16)hv;
    }
  }
  // yh[r][f] = h_T . W_out[f] + bout[f]  (one-time)
  if (t < DROWS * NF) {
    int r = t / NF, f = t - (t / NF) * NF;
    float a = bout[f];
    const float* wr = Wout + f * NH;
    const float* hp = hT + (size_t)(r0 + r) * NH;
    #pragma unroll 8
    for (int k = 0; k < NH; k += 4) {
      float4 pv = *(const float4*)(hp + k);
      float4 wv = *(const float4*)(wr + k);
      a += pv.x * wv.x + pv.y * wv.y + pv.z * wv.z + pv.w * wv.w;
    }
    sh_yh[t] = a;
  }
  __syncthreads();
  // d0[r][s] = (y0[r] - yh[r]) . W_att_y[s]  (step-0 correction)
  for (int i = t; i < DROWS * SEQ; i += NTHR) {
    int r = i / SEQ, s = i - (i / SEQ) * SEQ;
    float a = 0.f;
    #pragma unroll
    for (int f = 0; f < NF; ++f) {
      float y0f = xb[((size_t)(r0 + r) * SEQ + (SEQ - 1)) * NF + f];
      a += (y0f - sh_yh[r * NF + f]) * Watt[s * (NH + NF) + NH + f];
    }
    sh_d0[i] = a;
  }

  // D3 per-thread constants: each thread owns (dh) for rows dr and dr+4
  const int dr = t >> 7;          // 0..3 (wave-uniform)
  const int dh = t & 127;
  const unsigned int* hrowA = hist + (size_t)dr * (LS4 * NH) + dh;
  const unsigned int* hrowB = hist + (size_t)(dr + 4) * (LS4 * NH) + dh;
  const float* erowA = sh_attw + dr * SEQ;
  const float* erowB = sh_attw + (dr + 4) * SEQ;

  // step-invariant hist tail (s4 30..41) held in registers: 3x u32x4 per row
  u32x4 tA[3], tB[3];
  {
    const u32x4* e2 = (const u32x4*)encw2;
    #pragma unroll
    for (int b = 0; b < 3; ++b) {
      tA[b] = e2[((size_t)(r0 + dr)     * 3 + b) * NH + dh];
      tB[b] = e2[((size_t)(r0 + dr + 4) * 3 + b) * NH + dh];
    }
  }
  __syncthreads();

  for (int p = 0; p < NP; ++p) {
    const int CA = p & 1;

    // finalize previous step's output (partials written in prev D4)
    if (p > 0 && t < DROWS) {
      float a = bconstv;
      #pragma unroll
      for (int w2 = 0; w2 < 8; ++w2) a += sh_outp[w2 * 8 + t];
      out[(size_t)(r0 + t) * NP + (p - 1)] = a;
    }

    // D1: logits = prev_h @ Weff^T + beff (+d0 at p=0); e = exp(clamped)
    {
      h16x8 afA[4];
      #pragma unroll
      for (int kt = 0; kt < 4; ++kt)
        afA[kt] = *(const h16x8*)(sh_cath + CA * 8 * CTS + (ln & 7) * CTS + 128 + kt * 32 + lq * 8);
      f32x4 acc = {0.f, 0.f, 0.f, 0.f};
      #pragma unroll
      for (int kt = 0; kt < 4; ++kt)
        mfma_av(acc, afA[kt], bfA[kt]);
      if (act) {
        #pragma unroll
        for (int reg = 0; reg < 4; ++reg) {
          int row = lq * 4 + reg;
          float lg = acc[reg] + beffR;
          if (p == 0) lg += sh_d0[row * SEQ + hcol];
          lg = fminf(fmaxf(lg, -30.f), 30.f);
          sh_attw[row * SEQ + hcol] = __expf(lg);
        }
      }
      if (w < 3) {
        int srow = (s2v < SEQ ? s2v : SEQ - 1) - 128;
        f32x4 acc2 = {0.f, 0.f, 0.f, 0.f};
        #pragma unroll
        for (int kt = 0; kt < 4; ++kt) {
          h16x8 bf2 = *(const h16x8*)(sh_watt2 + srow * NH + kt * 32 + lq * 8);
          acc2 = __builtin_amdgcn_mfma_f32_16x16x32_f16(afA[kt], bf2, acc2, 0, 0, 0);
        }
        if (s2v < SEQ && act) {
          #pragma unroll
          for (int reg = 0; reg < 4; ++reg) {
            int row = lq * 4 + reg;
            float lg = acc2[reg] + beff2;
            if (p == 0) lg += sh_d0[row * SEQ + s2v];
            lg = fminf(fmaxf(lg, -30.f), 30.f);
            sh_attw[row * SEQ + s2v] = __expf(lg);
          }
        }
      }
    }
    __syncthreads();

    // D3: combine[r][h] = (Σ_s e_s v_s)/(Σ_s e_s); thread owns (dh) x rows {dr, dr+4}
    {
      // denominators via wave-wide shuffle reduce over sh_attw (rows are wave-uniform)
      float dA = erowA[l] + erowA[64 + l];
      float dB = erowB[l] + erowB[64 + l];
      if (l < SEQ - 128) { dA += erowA[128 + l]; dB += erowB[128 + l]; }
      #pragma unroll
      for (int k = 1; k < 64; k <<= 1) {
        dA += __shfl_xor(dA, k);
        dB += __shfl_xor(dB, k);
      }
      const float invA = 0.0625f / dA;
      const float invB = 0.0625f / dB;

      f32x2 avA = {0.f, 0.f};
      f32x2 avB = {0.f, 0.f};
      #pragma unroll 6
      for (int s4 = 0; s4 < LS4; ++s4) {
        unsigned int evA = hrowA[s4 * NH];
        unsigned int evB = hrowB[s4 * NH];
        float4 eA = *(const float4*)(erowA + s4 * 4);
        float4 eB = *(const float4*)(erowB + s4 * 4);
        f32x2 wA01 = {eA.x, eA.y}, wA23 = {eA.z, eA.w};
        f32x2 wB01 = {eB.x, eB.y}, wB23 = {eB.z, eB.w};
        avA = wA01 * unp2<false>(evA) + avA;
        avA = wA23 * unp2<true>(evA) + avA;
        avB = wB01 * unp2<false>(evB) + avB;
        avB = wB23 * unp2<true>(evB) + avB;
      }
      #pragma unroll
      for (int b = 0; b < 3; ++b) {
        #pragma unroll
        for (int jj = 0; jj < 4; ++jj) {
          int s4 = LS4 + b * 4 + jj;
          unsigned int evA = tA[b][jj];
          unsigned int evB = tB[b][jj];
          float4 eA = *(const float4*)(erowA + s4 * 4);
          float4 eB = *(const float4*)(erowB + s4 * 4);
          f32x2 wA01 = {eA.x, eA.y}, wA23 = {eA.z, eA.w};
          f32x2 wB01 = {eB.x, eB.y}, wB23 = {eB.z, eB.w};
          avA = wA01 * unp2<false>(evA) + avA;
          avA = wA23 * unp2<true>(evA) + avA;
          avB = wB01 * unp2<false>(evB) + avB;
          avB = wB23 * unp2<true>(evB) + avB;
        }
      }
      sh_cath[CA * 8 * CTS + dr * CTS + dh]       = (h16)((avA.x + avA.y) * invA);
      sh_cath[CA * 8 * CTS + (dr + 4) * CTS + dh] = (h16)((avB.x + avB.y) * invB);
    }
    __syncthreads();

    // D4+D5: gates via MFMA (i,f,g) with AGPR-resident B; cell in-register
    {
      f32x4 ag[3] = {{0.f,0.f,0.f,0.f},{0.f,0.f,0.f,0.f},{0.f,0.f,0.f,0.f}};
      #pragma unroll
      for (int kt = 0; kt < 8; ++kt) {
        h16x8 af = *(const h16x8*)(sh_cath + CA * 8 * CTS + (ln & 7) * CTS + kt * 32 + lq * 8);
        #pragma unroll
        for (int g = 0; g < 3; ++g)
          mfma_av(ag[g], af, bfD[g][kt]);
      }
      if (act) {
        float contrib[4];
        #pragma unroll
        for (int reg = 0; reg < 4; ++reg) {
          int row = lq * 4 + reg;
          float gi = sigm(ag[0][reg] + bD[0]);
          float gf = sigm(ag[1][reg] + bD[1]);
          float gg = tanh_(ag[2][reg] + bD[2]);
          float cn = gf * creg[reg] + gi * gg;
          creg[reg] = cn;
          sh_cath[(CA ^ 1) * 8 * CTS + row * CTS + 128 + hcol] = (h16)cn;
          contrib[reg] = cn * wcombR;
        }
        #pragma unroll
        for (int reg = 0; reg < 4; ++reg) {
          float rsum = contrib[reg];
          rsum += __shfl_xor(rsum, 1);
          rsum += __shfl_xor(rsum, 2);
          rsum += __shfl_xor(rsum, 4);
          rsum += __shfl_xor(rsum, 8);
          if (ln == 0) sh_outp[w * 8 + lq * 4 + reg] = rsum;
        }
      }
    }
    __syncthreads();
  }

  // finalize last output
  if (t < DROWS) {
    float a = bconstv;
    #pragma unroll
    for (int w2 = 0; w2 < 8; ++w2) a += sh_outp[w2 * 8 + t];
    out[(size_t)(r0 + t) * NP + (NP - 1)] = a;
  }
}

extern "C" void kernel_launch(void* const* d_in, const int* in_sizes, int n_in,
                              void* d_out, int out_size, void* d_ws, size_t ws_size,
                              hipStream_t stream) {
  const float* xb      = (const float*)d_in[0];
  const float* Wih_enc = (const float*)d_in[1];
  const float* Whh_enc = (const float*)d_in[2];
  const float* bih_enc = (const float*)d_in[3];
  const float* bhh_enc = (const float*)d_in[4];
  const float* Watt    = (const float*)d_in[5];
  const float* batt    = (const float*)d_in[6];
  const float* Wih_dec = (const float*)d_in[7];
  const float* Whh_dec = (const float*)d_in[8];
  const float* bih_dec = (const float*)d_in[9];
  const float* bhh_dec = (const float*)d_in[10];
  const float* Wout    = (const float*)d_in[11];
  const float* bout    = (const float*)d_in[12];
  const float* Wfin    = (const float*)d_in[13];
  const float* bfin    = (const float*)d_in[14];
  char* ws = (char*)d_ws;  // needs ~45.6 MB

  hipFuncSetAttribute(reinterpret_cast<const void*>(dec_kernel),
                      hipFuncAttributeMaxDynamicSharedMemorySize, DSMEM);

  // 81920+131072+21504+168+128+1+512 = 235305 -> 920 blocks
  setup_weights<<<920, 256, 0, stream>>>(Wih_enc, Whh_enc, Wih_dec, Whh_dec,
                                         Watt, batt, Wout, bout, Wfin, bfin,
                                         bih_enc, bhh_enc, bih_dec, bhh_dec, ws);
  enc_kernel<<<NB / EROWS, NTHR, 0, stream>>>(
      xb, (const h16*)(ws + WENC_OFF), (const float*)(ws + BENC_OFF),
      (unsigned int*)(ws + ENC_OFF), (unsigned int*)(ws + ENC2_OFF),
      (float*)(ws + HT_OFF));
  dec_kernel<<<NB / DROWS, NTHR, DSMEM, stream>>>(
      xb, Watt, Wout, bout,
      (const h16*)(ws + WDEC_OFF), (const h16*)(ws + WEFF_OFF),
      (const float*)(ws + BEFF_OFF), (const float*)(ws + WCOMB_OFF),
      (const float*)(ws + BCONST_OFF), (const float*)(ws + BDEC_OFF),
      (const unsigned int*)(ws + ENC_OFF), (const unsigned int*)(ws + ENC2_OFF),
      (const float*)(ws + HT_OFF), (float*)d_out);
}